// Round 10
// baseline (45.175 us; speedup 1.0000x reference)
//
#include <hip/hip_runtime.h>
#include <math.h>

// Sampler: iterative Gumbel-softmax relaxed top-k.
// att: [B=256, N=1024, M=4] f32; k=128; out: khot [B,N,M] f32.
// One WAVE per (b,m) column (64 lanes x 16 elems as 8 packed float2).
// Wall = 128 x per-iteration dependence chain. This round shortens the
// cross-lane segment: circular row_ror all-reduce (4 fused DPP adds ->
// every lane holds its 16-lane row sum) + THREE PARALLEL __shfl_xor
// (16/32/48) whose latencies overlap, + 2 adds -> all lanes hold S.
// No readlane / no SALU round-trip; rcp runs per-lane.
// kh += o_prev (materialized o) fills the shuffle window.
// w carries exp(2*ag - M0) exactly (verified R4-R9).
// PRNG: JAX threefry2x32 key (0,42), partitionable: counter (0,i),
// bits = out0 ^ out1 (verified R4).

#define N_NODES 1024

typedef float f2 __attribute__((ext_vector_type(2)));

__device__ __forceinline__ unsigned rotl32(unsigned x, int r) {
  return (x << r) | (x >> (32 - r));
}

// JAX/Random123 Threefry-2x32, 20 rounds.
__device__ __forceinline__ void threefry2x32(unsigned k0, unsigned k1,
                                             unsigned& x0, unsigned& x1) {
  const unsigned ks0 = k0, ks1 = k1, ks2 = k0 ^ k1 ^ 0x1BD11BDAu;
  x0 += ks0; x1 += ks1;
  x0 += x1; x1 = rotl32(x1, 13); x1 ^= x0;
  x0 += x1; x1 = rotl32(x1, 15); x1 ^= x0;
  x0 += x1; x1 = rotl32(x1, 26); x1 ^= x0;
  x0 += x1; x1 = rotl32(x1, 6);  x1 ^= x0;
  x0 += ks1; x1 += ks2 + 1u;
  x0 += x1; x1 = rotl32(x1, 17); x1 ^= x0;
  x0 += x1; x1 = rotl32(x1, 29); x1 ^= x0;
  x0 += x1; x1 = rotl32(x1, 16); x1 ^= x0;
  x0 += x1; x1 = rotl32(x1, 24); x1 ^= x0;
  x0 += ks2; x1 += ks0 + 2u;
  x0 += x1; x1 = rotl32(x1, 13); x1 ^= x0;
  x0 += x1; x1 = rotl32(x1, 15); x1 ^= x0;
  x0 += x1; x1 = rotl32(x1, 26); x1 ^= x0;
  x0 += x1; x1 = rotl32(x1, 6);  x1 ^= x0;
  x0 += ks0; x1 += ks1 + 3u;
  x0 += x1; x1 = rotl32(x1, 17); x1 ^= x0;
  x0 += x1; x1 = rotl32(x1, 29); x1 ^= x0;
  x0 += x1; x1 = rotl32(x1, 16); x1 ^= x0;
  x0 += x1; x1 = rotl32(x1, 24); x1 ^= x0;
  x0 += ks1; x1 += ks2 + 4u;
  x0 += x1; x1 = rotl32(x1, 13); x1 ^= x0;
  x0 += x1; x1 = rotl32(x1, 15); x1 ^= x0;
  x0 += x1; x1 = rotl32(x1, 26); x1 ^= x0;
  x0 += x1; x1 = rotl32(x1, 6);  x1 ^= x0;
  x0 += ks2; x1 += ks0 + 5u;
}

// Circular intra-row all-reduce: 4 fused v_add_f32+DPP row_ror steps.
// After this, EVERY lane of each 16-lane row holds its full row sum
// (ror is circular, so no bcast/readlane needed). s_nop 1 covers the
// VALU->DPP-source software hazard.
__device__ __forceinline__ float row_allreduce16(float v) {
  asm("s_nop 1\n\t"
      "v_add_f32 %0, %0, %0 row_ror:1\n\t"
      "s_nop 1\n\t"
      "v_add_f32 %0, %0, %0 row_ror:2\n\t"
      "s_nop 1\n\t"
      "v_add_f32 %0, %0, %0 row_ror:4\n\t"
      "s_nop 1\n\t"
      "v_add_f32 %0, %0, %0 row_ror:8\n\t"
      "s_nop 1"
      : "+v"(v));
  return v;
}

// max variant (used once in the prologue; builtin form is fine there)
template <int CTRL>
__device__ __forceinline__ float dpp_max_step(float v) {
  int iv = __float_as_int(v);
  int t = __builtin_amdgcn_update_dpp(iv, iv, CTRL, 0xf, 0xf, false);
  return fmaxf(v, __int_as_float(t));
}
__device__ __forceinline__ float wave_max64(float v) {
  v = dpp_max_step<0x111>(v);
  v = dpp_max_step<0x112>(v);
  v = dpp_max_step<0x114>(v);
  v = dpp_max_step<0x118>(v);
  v = dpp_max_step<0x142>(v);
  v = dpp_max_step<0x143>(v);
  return __int_as_float(__builtin_amdgcn_readlane(__float_as_int(v), 63));
}

__global__ __launch_bounds__(64, 1)
void Sampler_72619307040792_kernel(const float* __restrict__ att,
                                   const int* __restrict__ kp,
                                   float* __restrict__ out) {
  const int col = blockIdx.x;        // 0..1023 = b*4 + m; ONE wave per column
  const int b = col >> 2;
  const int m = col & 3;
  const int lane = threadIdx.x;      // 64 threads = 1 wave
  const int k = *kp;

  const float EPS = __uint_as_float(0x00800000u);  // f32 tiny (normal min)
  const int base = b * 4096 + m;     // + n*4 indexes element n of this column

  float g[16];
  f2 w[8], kh[8], o[8];

  // --- init: att + Gumbel noise (threefry partitionable, bits = x0^x1), x2
#pragma unroll
  for (int j = 0; j < 16; ++j) {
    const int n = j * 64 + lane;
    const unsigned idx = (unsigned)(base + n * 4);
    unsigned c0 = 0u, c1 = idx;
    threefry2x32(0u, 42u, c0, c1);
    const unsigned bits = c0 ^ c1;
    const float u = __uint_as_float((bits >> 9) | 0x3F800000u) - 1.0f;
    const float gum = -logf(-logf(u + EPS));
    g[j] = 2.0f * (att[idx] + gum);
  }

  // --- column max M0 (uniform shift; exact softmax equivalence)
  float mx = g[0];
#pragma unroll
  for (int j = 1; j < 16; ++j) mx = fmaxf(mx, g[j]);
  mx = wave_max64(mx);

  // --- w = exp(g - M0) packed; kh = 0; o = 0 (iter-0 kh-add is a no-op)
#pragma unroll
  for (int p = 0; p < 8; ++p) {
    f2 t;
    t.x = expf(g[2 * p] - mx);
    t.y = expf(g[2 * p + 1] - mx);
    w[p] = t;
    kh[p] = (f2)(0.0f);
    o[p] = (f2)(0.0f);
  }

  // --- k iterations:
  //   S = sum w (ror all-reduce + 3 parallel shfl_xor); rinv = rcp(S);
  //   kh += o_prev; o = w*rinv; w *= (1 - w*rinv)^2
  const f2 one = (f2)(1.0f);
  for (int it = 0; it < k; ++it) {
    // in-lane tree: 8 f2 -> 1 f2 (3 packed hops) -> scalar fold (1 hop)
    f2 s0 = w[0] + w[1];
    f2 s1 = w[2] + w[3];
    f2 s2 = w[4] + w[5];
    f2 s3 = w[6] + w[7];
    f2 sA = s0 + s1;
    f2 sB = s2 + s3;
    f2 sC = sA + sB;
    float sv = sC.x + sC.y;
    // intra-row circular all-reduce: every lane has its row's sum
    const float y = row_allreduce16(sv);
    // cross-row: three INDEPENDENT shuffles (latencies overlap)
    const float a16 = __shfl_xor(y, 16, 64);
    const float a32 = __shfl_xor(y, 32, 64);
    const float a48 = __shfl_xor(y, 48, 64);
    // fill the shuffle window with kh accumulation (independent)
#pragma unroll
    for (int p = 0; p < 8; ++p) kh[p] += o[p];
    // combine + rcp (identical value in every lane)
    const float S = (y + a16) + (a32 + a48);
    const float rinv = __builtin_amdgcn_rcpf(S);
    f2 rv;
    rv.x = rinv;
    rv.y = rinv;
    // o = w*rinv; w <- w*(1-w*rinv)^2
#pragma unroll
    for (int p = 0; p < 8; ++p) {
      const f2 u = __builtin_elementwise_fma(-w[p], rv, one);
      o[p] = w[p] * rv;
      const f2 u2 = u * u;
      w[p] = w[p] * u2;
    }
  }

  // --- final o accumulation + store
#pragma unroll
  for (int p = 0; p < 8; ++p) {
    kh[p] += o[p];
    out[base + (2 * p * 64 + lane) * 4] = kh[p].x;
    out[base + ((2 * p + 1) * 64 + lane) * 4] = kh[p].y;
  }
}

extern "C" void kernel_launch(void* const* d_in, const int* in_sizes, int n_in,
                              void* d_out, int out_size, void* d_ws, size_t ws_size,
                              hipStream_t stream) {
  const float* att = (const float*)d_in[0];
  const int* kp = (const int*)d_in[1];
  float* out = (float*)d_out;
  const int cols = out_size / N_NODES;  // 1024 columns, one wave each
  Sampler_72619307040792_kernel<<<cols, 64, 0, stream>>>(att, kp, out);
}

// Round 11
// 39.186 us; speedup vs baseline: 1.1528x; 1.1528x over previous
//
#include <hip/hip_runtime.h>
#include <math.h>

// Sampler: iterative Gumbel-softmax relaxed top-k.
// att: [B=256, N=1024, M=4] f32; k=128; out: khot [B,N,M] f32.
// One WAVE per (b,m) column (64 lanes x 16 elems as 8 packed float2).
//
// KEY RESTRUCTURE (this round): the per-iteration cross-lane sum is taken
// OFF the loop-carried critical path via exact moment algebra:
//   S_{t+1} = sum w_t (1 - w_t r_t)^2 = S_t - 2 r_t P_t + r_t^2 Q_t,
//   P_t = sum w_t^2, Q_t = sum w_t^3   (independent of r_t!)
// P,Q tree-partials are computed in iteration t-1's body, their DPP chains
// issue at the top of body t and are latency-hidden under ~90 independent
// VALU instrs; the carried spine is just 2 fma + rcp (~4 hops).
// First HEAD iterations use the verified direct-reduce body (guards the
// only cancellation-risky near-tower events, which occur at t=0..1).
// w carries exp(2*ag - M0) exactly (verified R4-R10).
// PRNG: JAX threefry2x32 key (0,42), partitionable: counter (0,i),
// bits = out0 ^ out1 (verified R4).

#define N_NODES 1024
#define HEAD 4

typedef float f2 __attribute__((ext_vector_type(2)));

__device__ __forceinline__ unsigned rotl32(unsigned x, int r) {
  return (x << r) | (x >> (32 - r));
}

// JAX/Random123 Threefry-2x32, 20 rounds.
__device__ __forceinline__ void threefry2x32(unsigned k0, unsigned k1,
                                             unsigned& x0, unsigned& x1) {
  const unsigned ks0 = k0, ks1 = k1, ks2 = k0 ^ k1 ^ 0x1BD11BDAu;
  x0 += ks0; x1 += ks1;
  x0 += x1; x1 = rotl32(x1, 13); x1 ^= x0;
  x0 += x1; x1 = rotl32(x1, 15); x1 ^= x0;
  x0 += x1; x1 = rotl32(x1, 26); x1 ^= x0;
  x0 += x1; x1 = rotl32(x1, 6);  x1 ^= x0;
  x0 += ks1; x1 += ks2 + 1u;
  x0 += x1; x1 = rotl32(x1, 17); x1 ^= x0;
  x0 += x1; x1 = rotl32(x1, 29); x1 ^= x0;
  x0 += x1; x1 = rotl32(x1, 16); x1 ^= x0;
  x0 += x1; x1 = rotl32(x1, 24); x1 ^= x0;
  x0 += ks2; x1 += ks0 + 2u;
  x0 += x1; x1 = rotl32(x1, 13); x1 ^= x0;
  x0 += x1; x1 = rotl32(x1, 15); x1 ^= x0;
  x0 += x1; x1 = rotl32(x1, 26); x1 ^= x0;
  x0 += x1; x1 = rotl32(x1, 6);  x1 ^= x0;
  x0 += ks0; x1 += ks1 + 3u;
  x0 += x1; x1 = rotl32(x1, 17); x1 ^= x0;
  x0 += x1; x1 = rotl32(x1, 29); x1 ^= x0;
  x0 += x1; x1 = rotl32(x1, 16); x1 ^= x0;
  x0 += x1; x1 = rotl32(x1, 24); x1 ^= x0;
  x0 += ks1; x1 += ks2 + 4u;
  x0 += x1; x1 = rotl32(x1, 13); x1 ^= x0;
  x0 += x1; x1 = rotl32(x1, 15); x1 ^= x0;
  x0 += x1; x1 = rotl32(x1, 26); x1 ^= x0;
  x0 += x1; x1 = rotl32(x1, 6);  x1 ^= x0;
  x0 += ks2; x1 += ks0 + 5u;
}

// --- DPP wave-64 reduction (builtin form: compiler fuses & schedules) --------
template <int CTRL>
__device__ __forceinline__ float dpp_sum_step(float v) {
  int t = __builtin_amdgcn_update_dpp(0, __float_as_int(v), CTRL, 0xf, 0xf, true);
  return v + __int_as_float(t);
}
template <int CTRL>
__device__ __forceinline__ float dpp_max_step(float v) {
  int iv = __float_as_int(v);
  int t = __builtin_amdgcn_update_dpp(iv, iv, CTRL, 0xf, 0xf, false);
  return fmaxf(v, __int_as_float(t));
}

__device__ __forceinline__ float wave_sum64(float v) {
  v = dpp_sum_step<0x111>(v);  // row_shr:1
  v = dpp_sum_step<0x112>(v);  // row_shr:2
  v = dpp_sum_step<0x114>(v);  // row_shr:4
  v = dpp_sum_step<0x118>(v);  // row_shr:8
  v = dpp_sum_step<0x142>(v);  // row_bcast:15
  v = dpp_sum_step<0x143>(v);  // row_bcast:31 -> lane 63 has full sum
  return __int_as_float(__builtin_amdgcn_readlane(__float_as_int(v), 63));
}
__device__ __forceinline__ float wave_max64(float v) {
  v = dpp_max_step<0x111>(v);
  v = dpp_max_step<0x112>(v);
  v = dpp_max_step<0x114>(v);
  v = dpp_max_step<0x118>(v);
  v = dpp_max_step<0x142>(v);
  v = dpp_max_step<0x143>(v);
  return __int_as_float(__builtin_amdgcn_readlane(__float_as_int(v), 63));
}

// in-lane pairwise tree: 8 f2 -> scalar
__device__ __forceinline__ float lane_tree8(const f2* a) {
  f2 s0 = a[0] + a[1];
  f2 s1 = a[2] + a[3];
  f2 s2 = a[4] + a[5];
  f2 s3 = a[6] + a[7];
  f2 sA = s0 + s1;
  f2 sB = s2 + s3;
  f2 sC = sA + sB;
  return sC.x + sC.y;
}

__global__ __launch_bounds__(64, 1)
void Sampler_72619307040792_kernel(const float* __restrict__ att,
                                   const int* __restrict__ kp,
                                   float* __restrict__ out) {
  const int col = blockIdx.x;        // 0..1023 = b*4 + m; ONE wave per column
  const int b = col >> 2;
  const int m = col & 3;
  const int lane = threadIdx.x;      // 64 threads = 1 wave
  const int k = *kp;

  const float EPS = __uint_as_float(0x00800000u);  // f32 tiny (normal min)
  const int base = b * 4096 + m;     // + n*4 indexes element n of this column

  float g[16];
  f2 w[8], kh[8];

  // --- init: att + Gumbel noise (threefry partitionable, bits = x0^x1), x2
#pragma unroll
  for (int j = 0; j < 16; ++j) {
    const int n = j * 64 + lane;
    const unsigned idx = (unsigned)(base + n * 4);
    unsigned c0 = 0u, c1 = idx;
    threefry2x32(0u, 42u, c0, c1);
    const unsigned bits = c0 ^ c1;
    const float u = __uint_as_float((bits >> 9) | 0x3F800000u) - 1.0f;
    const float gum = -logf(-logf(u + EPS));
    g[j] = 2.0f * (att[idx] + gum);
  }

  // --- column max M0 (uniform shift; exact softmax equivalence)
  float mx = g[0];
#pragma unroll
  for (int j = 1; j < 16; ++j) mx = fmaxf(mx, g[j]);
  mx = wave_max64(mx);

  // --- w = exp(g - M0) packed; kh = 0
#pragma unroll
  for (int p = 0; p < 8; ++p) {
    f2 t;
    t.x = expf(g[2 * p] - mx);
    t.y = expf(g[2 * p + 1] - mx);
    w[p] = t;
    kh[p] = (f2)(0.0f);
  }

  const f2 one = (f2)(1.0f);
  float S, r;

  // --- HEAD iterations: verified direct-reduce body (guards near-tower
  //     cancellation, which concentrates at the first selections)
  int it = 0;
  const int head = (k < HEAD) ? k : HEAD;
  for (; it < head; ++it) {
    S = wave_sum64(lane_tree8(w));
    r = __builtin_amdgcn_rcpf(S);
    f2 rv;
    rv.x = r;
    rv.y = r;
#pragma unroll
    for (int p = 0; p < 8; ++p)
      kh[p] = __builtin_elementwise_fma(w[p], rv, kh[p]);
#pragma unroll
    for (int p = 0; p < 8; ++p) {
      const f2 u = __builtin_elementwise_fma(-w[p], rv, one);
      const f2 t = w[p] * u;
      w[p] = t * u;
    }
  }

  // --- STEADY: software-pipelined moment recurrence
  if (it < k) {
    // transition: direct S for current w + in-lane moment partials
    S = wave_sum64(lane_tree8(w));
    r = __builtin_amdgcn_rcpf(S);
    f2 w2[8];
#pragma unroll
    for (int p = 0; p < 8; ++p) w2[p] = w[p] * w[p];
    float tp = lane_tree8(w2);
    f2 qa = (f2)(0.0f), qb = (f2)(0.0f);
#pragma unroll
    for (int p = 0; p < 8; p += 2) {
      qa = __builtin_elementwise_fma(w2[p], w[p], qa);
      qb = __builtin_elementwise_fma(w2[p + 1], w[p + 1], qb);
    }
    {
      const f2 qs = qa + qb;
      float tq = qs.x + qs.y;

      for (; it < k; ++it) {
        // cross-lane moments of CURRENT w_t (inputs one body old ->
        // DPP latency hides under the independent work below)
        const float P = wave_sum64(tp);
        const float Q = wave_sum64(tq);
        f2 rv;
        rv.x = r;
        rv.y = r;
        // kh += oh_t (old w)
#pragma unroll
        for (int p = 0; p < 8; ++p)
          kh[p] = __builtin_elementwise_fma(w[p], rv, kh[p]);
        // w <- w_{t+1} = w (1 - w r)^2  (cancellation-safe factored form)
#pragma unroll
        for (int p = 0; p < 8; ++p) {
          const f2 u = __builtin_elementwise_fma(-w[p], rv, one);
          const f2 t = w[p] * u;
          w[p] = t * u;
        }
        // in-lane moment partials of w_{t+1} (for next body's DPP)
#pragma unroll
        for (int p = 0; p < 8; ++p) w2[p] = w[p] * w[p];
        tp = lane_tree8(w2);
        qa = (f2)(0.0f);
        qb = (f2)(0.0f);
#pragma unroll
        for (int p = 0; p < 8; p += 2) {
          qa = __builtin_elementwise_fma(w2[p], w[p], qa);
          qb = __builtin_elementwise_fma(w2[p + 1], w[p + 1], qb);
        }
        const f2 qs2 = qa + qb;
        tq = qs2.x + qs2.y;
        // spine: S_{t+1} = S - 2 r P + r^2 Q (exact algebra); r_{t+1}
        const float c1 = fmaf(-2.0f * r, P, S);
        S = fmaf(r * r, Q, c1);
        r = __builtin_amdgcn_rcpf(S);
      }
    }
  }

  // --- store khot
#pragma unroll
  for (int p = 0; p < 8; ++p) {
    out[base + (2 * p * 64 + lane) * 4] = kh[p].x;
    out[base + ((2 * p + 1) * 64 + lane) * 4] = kh[p].y;
  }
}

extern "C" void kernel_launch(void* const* d_in, const int* in_sizes, int n_in,
                              void* d_out, int out_size, void* d_ws, size_t ws_size,
                              hipStream_t stream) {
  const float* att = (const float*)d_in[0];
  const int* kp = (const int*)d_in[1];
  float* out = (float*)d_out;
  const int cols = out_size / N_NODES;  // 1024 columns, one wave each
  Sampler_72619307040792_kernel<<<cols, 64, 0, stream>>>(att, kp, out);
}